// Round 6
// baseline (44.987 us; speedup 1.0000x reference)
//
#include <hip/hip_runtime.h>
#include <hip/hip_bf16.h>
#include <math.h>

#define BB 64
#define HH 80
#define WW 3000
#define RAD 16
#define TW 64             // output columns per strip
#define NLOAD 96          // loaded columns = TW + 2*16 halo
#define XSW 52            // Xs words/row: 48 data + 4 pad (52 % 32 == 20 -> b128 bank-spread)
#define HXS 116           // Hxp col stride: 112 raw rows + 4 pad (116 % 32 == 20 -> b128 bank-spread)
#define NSTRIP 47         // ceil(3000/64)
#define NT 640
#define EPSF 1e-8f

#define XS_WORDS (HH * XSW)             // 4160
#define HXP_OFF  XS_WORDS
#define HXP_WORDS (TW * HXS)            // 7424
#define ICH_OFF  (XS_WORDS + HXP_WORDS) // 11584
#define TOT_WORDS (ICH_OFF + HH)        // 11664 words = 46656 B -> 3 blocks/CU (30/32 waves)

typedef float f32x2 __attribute__((ext_vector_type(2)));
typedef float f32x4 __attribute__((ext_vector_type(4)));

__device__ __forceinline__ float bflo(uint32_t w) { return __uint_as_float(w << 16); }
__device__ __forceinline__ float bfhi(uint32_t w) { return __uint_as_float(w & 0xffff0000u); }
__device__ __forceinline__ uint32_t packbf2(float lo, float hi) {
    union { __hip_bfloat162 h2; uint32_t u; } u;
    u.h2 = __hip_bfloat162(__float2bfloat16(lo), __float2bfloat16(hi));
    return u.u;
}
// unpack a bf16-packed word into f32x2 {lo, hi} (2 VALU ops); pk_add accumulates both halves
__device__ __forceinline__ f32x2 uw(uint32_t w) {
    f32x2 r; r.x = bflo(w); r.y = bfhi(w); return r;
}

// compile-time-folding element selectors (named registers only — no arrays/unions)
#define E4(V, J) ((J) == 0 ? (V).x : ((J) == 1 ? (V).y : ((J) == 2 ? (V).z : (V).w)))
#define W20(Q) E4((Q) < 4 ? v0 : (Q) < 8 ? v1 : (Q) < 12 ? v2 : (Q) < 16 ? v3 : v4, (Q) & 3)
#define W40(Q) E4((Q) < 4 ? v0 : (Q) < 8 ? v1 : (Q) < 12 ? v2 : (Q) < 16 ? v3 : (Q) < 20 ? v4 : \
                  (Q) < 24 ? v5 : (Q) < 28 ? v6 : (Q) < 32 ? v7 : (Q) < 36 ? v8 : v9, (Q) & 3)

__global__ __launch_bounds__(NT, 6)
void localnorm_kernel(const float* __restrict__ in, float* __restrict__ out) {
    extern __shared__ uint32_t smem[];
    uint32_t* Hxp = smem + HXP_OFF;          // Hxp[col][raw_r] at col*HXS + raw_r; raw_r = logical+16
    float* inv_ch = (float*)(smem + ICH_OFF);

    const int t     = threadIdx.x;
    const int strip = blockIdx.x % NSTRIP;
    const int b     = blockIdx.x / NSTRIP;
    const int c0    = strip * TW;

    // phase 0: per-row reciprocals + zero Hxp pad rows (raw 0..15 and 96..111) for 64 cols
    if (t < HH) {
        int lo = max(t - RAD, 0), hi = min(t + RAD, HH - 1);
        inv_ch[t] = 1.0f / (float)(hi - lo + 1);
    }
    if (t < 512) {
        const int col = t >> 3;
        const int c8  = t & 7;
        const int off = col * HXS + ((c8 < 4) ? (c8 * 4) : (96 + (c8 - 4) * 4));
        *(uint4*)(Hxp + off) = make_uint4(0u, 0u, 0u, 0u);
    }

    // phase 1: load 96 cols x 80 rows, pack to bf16 pairs. 80 rows x 24 quads = 1920 = 3*640.
    {
        const float* inb = in + (size_t)b * (HH * WW);
        #pragma unroll
        for (int it = 0; it < 3; ++it) {
            const int id  = t + it * NT;
            const int row = id / 24;
            const int q   = id - row * 24;
            const int gc  = c0 - 16 + 4 * q;
            uint2 w2;
            if (gc >= 0 && gc + 4 <= WW) {
                float4 v = *(const float4*)(inb + (size_t)row * WW + gc);
                w2.x = packbf2(v.x, v.y);
                w2.y = packbf2(v.z, v.w);
            } else {
                float p0 = (gc     >= 0 && gc     < WW) ? inb[(size_t)row * WW + gc]     : 0.f;
                float p1 = (gc + 1 >= 0 && gc + 1 < WW) ? inb[(size_t)row * WW + gc + 1] : 0.f;
                float p2 = (gc + 2 >= 0 && gc + 2 < WW) ? inb[(size_t)row * WW + gc + 2] : 0.f;
                float p3 = (gc + 3 >= 0 && gc + 3 < WW) ? inb[(size_t)row * WW + gc + 3] : 0.f;
                w2.x = packbf2(p0, p1);
                w2.y = packbf2(p2, p3);
            }
            *(uint2*)(smem + row * XSW + 2 * q) = w2;
        }
    }
    __syncthreads();

    // phase 2: fused horizontal 33-tap sums of x AND x^2; bf16-packed (Sx,Sxx) word per col.
    // 80 rows x 8 segs of 8 cols = 640 threads exactly; 5 b128 reads each.
    {
        const int row = t % HH;
        const int seg = t / HH;       // 0..7
        const uint32_t* xr = smem + row * XSW + seg * 4;
        uint4 v0 = *(const uint4*)(xr);
        uint4 v1 = *(const uint4*)(xr + 4);
        uint4 v2 = *(const uint4*)(xr + 8);
        uint4 v3 = *(const uint4*)(xr + 12);
        uint4 v4 = *(const uint4*)(xr + 16);
        // initial window e0..e32: packed pair accumulate, 2-way ILP split
        float l16 = bflo(W20(16));
        f32x2 pA; pA.x = l16;       pA.y = 0.f;
        f32x2 qA; qA.x = l16 * l16; qA.y = 0.f;
        f32x2 pB; pB.x = 0.f; pB.y = 0.f;
        f32x2 qB; qB.x = 0.f; qB.y = 0.f;
        #pragma unroll
        for (int q = 0; q < 16; q += 2) {
            f32x2 uA = uw(W20(q));
            f32x2 uB = uw(W20(q + 1));
            pA += uA;      pB += uB;
            qA += uA * uA; qB += uB * uB;
        }
        f32x2 ps = pA + pB, qs = qA + qB;
        float ax  = ps.x + ps.y;
        float axx = qs.x + qs.y;
        uint32_t* hw = Hxp + (seg * 8) * HXS + row + 16;
        #pragma unroll
        for (int k = 0; k < 4; ++k) {
            uint32_t wS = W20(k), wE = W20(k + 16);
            float lS = bflo(wS), hE = bfhi(wE);
            float a1x  = ax - lS + hE;
            float a1xx = axx - lS * lS + hE * hE;
            hw[(2 * k) * HXS]     = packbf2(ax, axx);
            hw[(2 * k + 1) * HXS] = packbf2(a1x, a1xx);
            if (k != 3) {
                float hS = bfhi(wS), lN = bflo(W20(k + 17));
                ax  = a1x - hS + lN;
                axx = a1xx - hS * hS + lN * lN;
            }
        }
    }
    __syncthreads();

    // phase 3: vertical 33-tap sums of (Sx,Sxx) via pk_add; normalize, f32 store.
    // 64 cols x 10 bands of 8 rows = 640 threads exactly; 10 contiguous b128 reads.
    {
        const int c    = t & 63;
        const int band = t >> 6;      // 0..9
        const int gc   = c0 + c;
        if (gc < WW) {
            const int r0 = band * 8;
            const uint32_t* hp = Hxp + c * HXS + r0;   // raw rows r0 .. r0+39
            uint4 v0 = *(const uint4*)(hp);
            uint4 v1 = *(const uint4*)(hp + 4);
            uint4 v2 = *(const uint4*)(hp + 8);
            uint4 v3 = *(const uint4*)(hp + 12);
            uint4 v4 = *(const uint4*)(hp + 16);
            uint4 v5 = *(const uint4*)(hp + 20);
            uint4 v6 = *(const uint4*)(hp + 24);
            uint4 v7 = *(const uint4*)(hp + 28);
            uint4 v8 = *(const uint4*)(hp + 32);
            uint4 v9 = *(const uint4*)(hp + 36);
            // init acc = sum of words 0..32 (3 ops/word via pk_add), 2-way split
            f32x2 aA = uw(W40(32));
            f32x2 aB; aB.x = 0.f; aB.y = 0.f;
            #pragma unroll
            for (int q = 0; q < 32; q += 2) {
                aA += uw(W40(q));
                aB += uw(W40(q + 1));
            }
            f32x2 acc = aA + aB;                       // {Sx_v, Sxx_v}
            const float icw = 1.0f / (float)(min(gc + RAD, WW - 1) - max(gc - RAD, 0) + 1);
            f32x4 f4a = *(const f32x4*)(inv_ch + r0);
            f32x4 f4b = *(const f32x4*)(inv_ch + r0 + 4);
            const int  xwoff  = (c + 16) >> 1;
            const bool hiHalf = ((c + 16) & 1) != 0;
            float* outb = out + (size_t)b * (HH * WW);
            #pragma unroll
            for (int k = 0; k < 8; ++k) {
                const int r = r0 + k;
                const float ninv = E4(k < 4 ? f4a : f4b, k & 3) * icw;
                float mean = acc.x * ninv;
                float exx  = acc.y * ninv;
                float var  = fmaxf(exx - mean * mean, 0.f);
                float sd   = __builtin_amdgcn_sqrtf(var);
                uint32_t xw = smem[r * XSW + xwoff];
                float xv = hiHalf ? bfhi(xw) : bflo(xw);
                outb[(size_t)r * WW + gc] = (xv - mean) * __builtin_amdgcn_rcpf(sd + EPSF);
                if (k != 7) {
                    acc += uw(W40(k + 33)) - uw(W40(k));   // 2x v_pk_add_f32
                }
            }
        }
    }
}

extern "C" void kernel_launch(void* const* d_in, const int* in_sizes, int n_in,
                              void* d_out, int out_size, void* d_ws, size_t ws_size,
                              hipStream_t stream) {
    const float* in = (const float*)d_in[0];
    float* out = (float*)d_out;

    const size_t lds_bytes = (size_t)TOT_WORDS * sizeof(uint32_t);  // 46656
    static bool attr_set = false;
    if (!attr_set) {
        (void)hipFuncSetAttribute((const void*)localnorm_kernel,
                                  hipFuncAttributeMaxDynamicSharedMemorySize,
                                  (int)lds_bytes);
        attr_set = true;
    }

    dim3 grid(BB * NSTRIP);
    dim3 block(NT);
    localnorm_kernel<<<grid, block, lds_bytes, stream>>>(in, out);
}